// Round 8
// baseline (506.610 us; speedup 1.0000x reference)
//
#include <hip/hip_runtime.h>

#define U 20

struct Ptrs { const float* p[16]; };

// ============ Kernel A: MLPs -> f1/f2 (dense) + band values dense in ws ====
// ws layout (floats): ws1 = out1 bands, total*18 ; ws2 = out2 g2 bands, total*180.
__launch_bounds__(64)
__global__ void mlp_compute(const float* __restrict__ x, Ptrs pt,
                            float* __restrict__ out, float* __restrict__ ws,
                            int B, int total) {
    const int t = blockIdx.x * 64 + threadIdx.x;
    if (t >= total) return;
    const int b = t / U;
    const int i = t - b * U;

    const float* W1a = pt.p[0];  const float* b1a = pt.p[1];
    const float* W1b = pt.p[2];  const float* b1b = pt.p[3];
    const float* W1c = pt.p[4];  const float* b1c = pt.p[5];
    const float* W1d = pt.p[6];  const float* b1d = pt.p[7];
    const float* W2a = pt.p[8];  const float* b2a = pt.p[9];
    const float* W2b = pt.p[10]; const float* b2b = pt.p[11];
    const float* W2c = pt.p[12]; const float* b2c = pt.p[13];
    const float* W2d = pt.p[14]; const float* b2d = pt.p[15];

    const float* xb = x + (size_t)b * U;
    const int im = (i == 0)     ? U - 1 : i - 1;
    const int ip = (i == U - 1) ? 0     : i + 1;
    const float v0 = xb[im], v1 = xb[i], v2 = xb[ip];

    float h1[16], h2[32], h3[16];

    // ================= MLP 1 =================
    #pragma unroll
    for (int n = 0; n < 16; n++)
        h1[n] = fmaxf(b1a[n] + v0 * W1a[n] + v1 * W1a[16 + n] + v2 * W1a[32 + n], 0.f);
    #pragma unroll
    for (int n = 0; n < 32; n++) h2[n] = b1b[n];
    #pragma unroll
    for (int k = 0; k < 16; k++) {
        float hk = h1[k];
        #pragma unroll
        for (int n = 0; n < 32; n++) h2[n] += hk * W1b[k * 32 + n];
    }
    #pragma unroll
    for (int n = 0; n < 32; n++) h2[n] = fmaxf(h2[n], 0.f);
    #pragma unroll
    for (int n = 0; n < 16; n++) h3[n] = b1c[n];
    #pragma unroll
    for (int k = 0; k < 32; k++) {
        float hk = h2[k];
        #pragma unroll
        for (int n = 0; n < 16; n++) h3[n] += hk * W1c[k * 16 + n];
    }
    #pragma unroll
    for (int n = 0; n < 16; n++) h3[n] = fmaxf(h3[n], 0.f);
    {
        float o1[19];
        #pragma unroll
        for (int n = 0; n < 19; n++) o1[n] = b1d[n];
        #pragma unroll
        for (int k = 0; k < 16; k++) {
            float hk = h3[k];
            #pragma unroll
            for (int n = 0; n < 19; n++) o1[n] += hk * W1d[k * 19 + n];
        }
        out[t] = o1[0];                               // f1 dense
        float2* d = reinterpret_cast<float2*>(ws + (size_t)t * 18);
        #pragma unroll
        for (int m = 0; m < 9; m++) {
            float2 v; v.x = o1[1 + 2 * m]; v.y = o1[2 + 2 * m];
            d[m] = v;
        }
    }

    // ================= MLP 2 =================
    #pragma unroll
    for (int n = 0; n < 16; n++)
        h1[n] = fmaxf(b2a[n] + v0 * W2a[n] + v1 * W2a[16 + n] + v2 * W2a[32 + n], 0.f);
    #pragma unroll
    for (int n = 0; n < 32; n++) h2[n] = b2b[n];
    #pragma unroll
    for (int k = 0; k < 16; k++) {
        float hk = h1[k];
        #pragma unroll
        for (int n = 0; n < 32; n++) h2[n] += hk * W2b[k * 32 + n];
    }
    #pragma unroll
    for (int n = 0; n < 32; n++) h2[n] = fmaxf(h2[n], 0.f);
    #pragma unroll
    for (int n = 0; n < 16; n++) h3[n] = b2c[n];
    #pragma unroll
    for (int k = 0; k < 32; k++) {
        float hk = h2[k];
        #pragma unroll
        for (int n = 0; n < 16; n++) h3[n] += hk * W2c[k * 16 + n];
    }
    #pragma unroll
    for (int n = 0; n < 16; n++) h3[n] = fmaxf(h3[n], 0.f);

    // f2 dense
    {
        const size_t f2_off = (size_t)B * 2420;
        float o2a[6];
        #pragma unroll
        for (int n = 0; n < 6; n++) o2a[n] = b2d[n];
        #pragma unroll
        for (int k = 0; k < 16; k++) {
            float hk = h3[k];
            #pragma unroll
            for (int n = 0; n < 6; n++) o2a[n] += hk * W2d[k * 186 + n];
        }
        float2* d = reinterpret_cast<float2*>(out + f2_off + (size_t)t * 6);
        #pragma unroll
        for (int m = 0; m < 3; m++) {
            float2 v; v.x = o2a[2 * m]; v.y = o2a[2 * m + 1];
            d[m] = v;
        }
    }

    // g2 band values dense: ws2[t*180 + z*30 + n]
    float* w2dst = ws + (size_t)total * 18 + (size_t)t * 180;
    #pragma unroll 1
    for (int z = 0; z < 6; z++) {
        float o2[30];
        #pragma unroll
        for (int n = 0; n < 30; n++) o2[n] = b2d[6 + z * 30 + n];
        #pragma unroll
        for (int k = 0; k < 16; k++) {
            float hk = h3[k];
            #pragma unroll
            for (int n = 0; n < 30; n++) o2[n] += hk * W2d[k * 186 + 6 + z * 30 + n];
        }
        float2* d = reinterpret_cast<float2*>(w2dst + z * 30);
        #pragma unroll
        for (int m = 0; m < 15; m++) {
            float2 v; v.x = o2[2 * m]; v.y = o2[2 * m + 1];
            d[m] = v;
        }
    }
}

// ============ Kernel B: high-occupancy row expander =========================
// One thread per output row: rid < total -> g1 row; else g2 row q = rid-total.
// Zero the 480 B row (float4), then overwrite the band from dense ws.
__launch_bounds__(256)
__global__ void expand(const float* __restrict__ ws, float* __restrict__ out,
                       int B, int total) {
    const int rid = blockIdx.x * 256 + threadIdx.x;
    const size_t g1_off = (size_t)B * 20;
    const size_t g2_off = (size_t)B * 2540;
    float4 z4; z4.x = z4.y = z4.z = z4.w = 0.f;

    if (rid < total) {
        const int t = rid;
        const int i = t % U;
        float* row = out + g1_off + (size_t)t * 120;
        float4* rv = reinterpret_cast<float4*>(row);
        #pragma unroll
        for (int m = 0; m < 30; m++) rv[m] = z4;
        const float2* src = reinterpret_cast<const float2*>(ws + (size_t)t * 18);
        #pragma unroll
        for (int j = 0; j < 3; j++) {
            int cc = i - 1 + j; if (cc < 0) cc += U; if (cc >= U) cc -= U;
            float2* d = reinterpret_cast<float2*>(row + cc * 6);
            d[0] = src[j * 3 + 0];
            d[1] = src[j * 3 + 1];
            d[2] = src[j * 3 + 2];
        }
    } else {
        const int q = rid - total;          // 0 .. total*6-1
        if (q < total * 6) {
            const int t = q / 6;
            const int z = q - 6 * t;
            const int i = t % U;
            float* row = out + g2_off + (size_t)q * 120;
            float4* rv = reinterpret_cast<float4*>(row);
            #pragma unroll
            for (int m = 0; m < 30; m++) rv[m] = z4;
            const float2* src = reinterpret_cast<const float2*>(
                ws + (size_t)total * 18 + (size_t)t * 180 + z * 30);
            #pragma unroll
            for (int j = 0; j < 5; j++) {
                int cc = i - 2 + j; if (cc < 0) cc += U; if (cc >= U) cc -= U;
                float2* d = reinterpret_cast<float2*>(row + cc * 6);
                d[0] = src[j * 3 + 0];
                d[1] = src[j * 3 + 1];
                d[2] = src[j * 3 + 2];
            }
        }
    }
}

extern "C" void kernel_launch(void* const* d_in, const int* in_sizes, int n_in,
                              void* d_out, int out_size, void* d_ws, size_t ws_size,
                              hipStream_t stream) {
    const float* x = (const float*)d_in[0];
    Ptrs pt;
    for (int a = 0; a < 16; a++) pt.p[a] = (const float*)d_in[1 + a];

    int total = in_sizes[0];      // B * 20
    int B = total / U;

    int blocksA = (total + 63) / 64;               // 5 waves/CU, balanced
    mlp_compute<<<blocksA, 64, 0, stream>>>(x, pt, (float*)d_out, (float*)d_ws,
                                            B, total);

    int rows = total * 7;                          // g1 rows + 6 g2 rows per unit
    int blocksB = (rows + 255) / 256;              // 35 waves/CU
    expand<<<blocksB, 256, 0, stream>>>((const float*)d_ws, (float*)d_out,
                                        B, total);
}